// Round 22
// baseline (962.100 us; speedup 1.0000x reference)
//
#include <hip/hip_runtime.h>
#include <hip/hip_bf16.h>
#include <cstdint>
#include <cstddef>

// GCNEncoder: two-branch GCN on MI355X.
// Round 22: exact round-20 structure (850us best) + PCH=512 only (pool_reduce
// halves; Spart 12.8MB fits dead partL alias). Round-21 lesson: role fusion
// inherits the max LDS footprint (cvt blocks got capped at 3/CU by hist's 50KB).
// Pipeline:
//   1) memset c_l/c_g (25.6MB)
//   2) cvt W -> bf16 Wt[512][2112]
//   3) k_hist -> k_prefix -> k_scan1(+bounds)
//   4) k_gemm_scat: GEMM blocks [0,782) (fp8 C-write) + scatter blocks
//      [782,1550) (LDS-rank sort -> packed er + fused c atomicAdd)
//   5) k_agg: CSR pull, wave/node, 16-deep fp8 gather
//   6) k_pool2 (PCH=512): Spart = c^T @ xl; k_pool_reduce -> S
//   7) k_final: (S@W2)/cnt + b2, concat, @W_fuse + b_fuse, relu -> out[64x128]

#define N_NODES 50000
#define N_GRAPHS 64
#define IN_DIM 2063
#define HIDDEN 256
#define OUT_DIM 128
#define EDGES_L 800000
#define EDGES_G 1600000
#define HCOLS 512   // [local 0..255 | global 256..511]
#define KPAD 2112   // 66 * 32
#define MPAD 50048  // 782 * 64
#define GBM 64      // GEMM M-tile
#define NGB (MPAD / GBM)                         // 782 GEMM blocks
#define NT (KPAD / 32)                           // 66 K-steps
#define PCH 512                                  // nodes per pool2 chunk
#define NCHUNK ((N_NODES + PCH - 1) / PCH)       // 98

// histogram geometry
#define QUARTER 12544                 // 4*12544 = 50176 >= N_NODES
#define SL_L 64                       // slices (L): 800000/64  = 12500 edges
#define SL_G 128                      // slices (G): 1600000/128 = 12500 edges
#define EPS 12500                     // edges per slice
#define HBLOCKS (4 * (SL_L + SL_G))   // 768 scatter blocks

typedef __attribute__((ext_vector_type(8))) __bf16 bf16x8;
typedef __attribute__((ext_vector_type(4))) float f32x4;

__device__ __forceinline__ float bf2f(unsigned short u) {
  union { unsigned int i; float f; } c; c.i = ((unsigned int)u) << 16; return c.f;
}
__device__ __forceinline__ unsigned short f2bf(float f) {
  __hip_bfloat16 h = __float2bfloat16(f);
  return *reinterpret_cast<unsigned short*>(&h);
}
__device__ __forceinline__ unsigned char f2fp8(float f) {
  return (unsigned char)(__builtin_amdgcn_cvt_pk_fp8_f32(f, f, 0, 0) & 0xff);
}

// ---------------------------------------------------------------- converts
__global__ void k_cvt_w(const float* __restrict__ Wl, const float* __restrict__ Wg,
                        unsigned short* __restrict__ Wt) {
  int i = blockIdx.x * blockDim.x + threadIdx.x;
  if (i >= HCOLS * KPAD) return;
  int n = i / KPAD;
  int k = i - n * KPAD;
  float v = 0.f;
  if (k < IN_DIM) {
    v = (n < HIDDEN) ? Wl[(size_t)k * HIDDEN + n] : Wg[(size_t)k * HIDDEN + (n - HIDDEN)];
  }
  Wt[(size_t)n * KPAD + k] = f2bf(v);
}

// ---------------- hist: LDS-private degree histogram, partials to global (no atomics)
__launch_bounds__(256)
__global__ void k_hist(const int* __restrict__ dstL, const int* __restrict__ dstG,
                       int* __restrict__ partL, int* __restrict__ partG) {
  __shared__ int hist[QUARTER];  // 50176 B
  const int i = blockIdx.x;
  const int* __restrict__ dst;
  int slice, q;
  int* __restrict__ part;
  if (i < 4 * SL_L) {
    slice = i >> 2; q = i & 3;
    dst = dstL;
    part = partL + (size_t)(slice * 4 + q) * QUARTER;
  } else {
    int j = i - 4 * SL_L;
    slice = j >> 2; q = j & 3;
    dst = dstG;
    part = partG + (size_t)(slice * 4 + q) * QUARTER;
  }
  for (int t = threadIdx.x; t < QUARTER; t += 256) hist[t] = 0;
  __syncthreads();
  const int e0 = slice * EPS;
  const int qbase = q * QUARTER;
  for (int e = e0 + threadIdx.x; e < e0 + EPS; e += 256) {
    int d = dst[e] - qbase;
    if ((unsigned)d < QUARTER) atomicAdd(&hist[d], 1);
  }
  __syncthreads();
  for (int t = threadIdx.x; t < QUARTER; t += 256) part[t] = hist[t];
}

// -------- prefix: per-(branch,node) scan over slices; emits deg/dinv/self-c; rewrites
// partials in place to exclusive per-slice offsets.
__global__ void k_prefix(int* __restrict__ partL, int* __restrict__ partG,
                         const int* __restrict__ batch, int* __restrict__ degL,
                         int* __restrict__ degG, float* __restrict__ dinvL,
                         float* __restrict__ dinvG, float* __restrict__ cL,
                         float* __restrict__ cG) {
  int t = blockIdx.x * blockDim.x + threadIdx.x;  // 0 .. 2*4*QUARTER-1
  if (t >= 8 * QUARTER) return;
  const int b = t / (4 * QUARTER);           // 0=L, 1=G
  const int n = t - b * 4 * QUARTER;         // node 0..50175
  const int q = n / QUARTER, loc = n - q * QUARTER;
  const int NS = b ? SL_G : SL_L;
  int* p = (b ? partG : partL) + (size_t)q * QUARTER + loc;
  int run = 0;
  for (int s = 0; s < NS; s++) {
    int* pp = p + (size_t)s * 4 * QUARTER;
    int v = *pp;
    *pp = run;
    run += v;
  }
  if (n < N_NODES) {
    float d = 1.0f / sqrtf((float)(run + 1));
    if (b == 0) {
      degL[n] = run; dinvL[n] = d; cL[(size_t)n * 64 + batch[n]] = d * d;
    } else {
      degG[n] = run; dinvG[n] = d; cG[(size_t)n * 64 + batch[n]] = d * d;
    }
  }
}

// ------- scan1: blocks 0,1 = exclusive degree scan -> row_ptr; blocks 2..50 = bounds
__global__ void k_scan1(const int* __restrict__ degL, const int* __restrict__ degG,
                        int* __restrict__ rowL, int* __restrict__ rowG,
                        const int* __restrict__ batch, int* __restrict__ start) {
  if (blockIdx.x >= 2) {
    int n = (blockIdx.x - 2) * 1024 + threadIdx.x;
    if (n >= N_NODES) return;
    int bn = batch[n];
    int bp = n ? batch[n - 1] : -1;
    for (int g = bp + 1; g <= bn; g++) start[g] = n;
    if (n == N_NODES - 1)
      for (int g = bn + 1; g <= N_GRAPHS; g++) start[g] = N_NODES;
    return;
  }
  __shared__ int part[1024];
  const int t = threadIdx.x;
  const int* __restrict__ deg = blockIdx.x ? degG : degL;
  int* __restrict__ row = blockIdx.x ? rowG : rowL;
  const int c0 = t * 49;  // 49*1024 = 50176 >= 50000
  int s = 0;
  for (int j = 0; j < 49; j++) {
    int idx = c0 + j;
    s += (idx < N_NODES) ? deg[idx] : 0;
  }
  part[t] = s;
  __syncthreads();
  for (int ofs = 1; ofs < 1024; ofs <<= 1) {
    int v = (t >= ofs) ? part[t - ofs] : 0;
    __syncthreads();
    part[t] += v;
    __syncthreads();
  }
  int run = (t > 0) ? part[t - 1] : 0;
  for (int j = 0; j < 49; j++) {
    int idx = c0 + j;
    if (idx < N_NODES) { row[idx] = run; run += deg[idx]; }
  }
  if (t == 1023) row[N_NODES] = part[1023];
}

// ------------------- FUSED: GEMM blocks [0,NGB) then scatter blocks [NGB,+HBLOCKS)
__launch_bounds__(256)
__global__ void k_gemm_scat(const float* __restrict__ X,
                            const unsigned short* __restrict__ Wt,
                            unsigned char* __restrict__ H,
                            const int* __restrict__ srcL, const int* __restrict__ dstL,
                            const int* __restrict__ srcG, const int* __restrict__ dstG,
                            const int* __restrict__ partL, const int* __restrict__ partG,
                            const int* __restrict__ rowL, const int* __restrict__ rowG,
                            const float* __restrict__ dinvL, const float* __restrict__ dinvG,
                            const int* __restrict__ batch, uint* __restrict__ erL,
                            uint* __restrict__ erG, float* __restrict__ cL,
                            float* __restrict__ cG) {
  __shared__ __align__(16) char lds[2 * 4096 + 2 * 32768];  // 72KB (role union)

  if (blockIdx.x >= NGB) {
    // -------- scatter role: packed er (src:16 | bf16 norm:16) + c atomicAdd --------
    int* hist = (int*)lds;
    const int i = blockIdx.x - NGB;
    const int *src, *dst, *part, *row;
    const float* dinv;
    uint* er;
    float* c;
    int slice, q;
    if (i < 4 * SL_L) {
      slice = i >> 2; q = i & 3;
      src = srcL; dst = dstL; row = rowL; dinv = dinvL; er = erL; c = cL;
      part = partL + (size_t)(slice * 4 + q) * QUARTER;
    } else {
      int j = i - 4 * SL_L;
      slice = j >> 2; q = j & 3;
      src = srcG; dst = dstG; row = rowG; dinv = dinvG; er = erG; c = cG;
      part = partG + (size_t)(slice * 4 + q) * QUARTER;
    }
    for (int t = threadIdx.x; t < QUARTER; t += 256) hist[t] = 0;
    __syncthreads();
    const int e0 = slice * EPS;
    const int qbase = q * QUARTER;
    for (int e = e0 + threadIdx.x; e < e0 + EPS; e += 256) {
      int d = dst[e];
      int loc = d - qbase;
      if ((unsigned)loc < QUARTER) {
        int s = src[e];
        int rank = atomicAdd(&hist[loc], 1);  // LDS atomic
        int pos = row[d] + part[loc] + rank;
        float nrm = dinv[s] * dinv[d];
        er[pos] = (uint)s | ((uint)f2bf(nrm) << 16);
        atomicAdd(&c[(size_t)s * 64 + batch[d]], nrm);
      }
    }
    return;
  }

  // ---------------- GEMM role ----------------
  char* const Ab0 = lds;
  char* const Ab1 = lds + 4096;
  char* const Bb0 = lds + 8192;
  char* const Bb1 = lds + 8192 + 32768;
  const int tid = threadIdx.x;
  const int lane = tid & 63;
  const int wave = tid >> 6;
  const int brow = blockIdx.x * GBM;

  const int ar = tid >> 2;
  const int ach = tid & 3;
  const int askew = (ar >> 1) & 3;
  const int asrc = (ach ^ askew) * 8;
  const int arow_g = brow + ar;
  const bool aok = arow_g < N_NODES;
  const float* __restrict__ Arow = X + (size_t)arow_g * IN_DIM;

  const int fr = lane & 15;
  const int fq = lane >> 4;

  f32x4 acc[4][8];
  const f32x4 zero = {0.f, 0.f, 0.f, 0.f};
#pragma unroll
  for (int m = 0; m < 4; m++)
#pragma unroll
    for (int n = 0; n < 8; n++) acc[m][n] = zero;

  // prologue: B(0) into Bb0; A(0) regs -> pack -> Ab0
#pragma unroll
  for (int i = 0; i < 8; i++) {
    const int s = i * 256 + tid;
    const int row = s >> 2, cch = s & 3;
    const unsigned short* g = Wt + (size_t)row * KPAD + ((cch ^ ((row >> 1) & 3)) * 8);
    __builtin_amdgcn_global_load_lds(
        (const __attribute__((address_space(1))) void*)g,
        (__attribute__((address_space(3))) void*)(Bb0 + (i * 256 + wave * 64) * 16),
        16, 0, 0);
  }
  float a[8];
#pragma unroll
  for (int j = 0; j < 8; j++) a[j] = aok ? Arow[asrc + j] : 0.f;
  {
    uint u0 = (uint)f2bf(a[0]) | ((uint)f2bf(a[1]) << 16);
    uint u1 = (uint)f2bf(a[2]) | ((uint)f2bf(a[3]) << 16);
    uint u2 = (uint)f2bf(a[4]) | ((uint)f2bf(a[5]) << 16);
    uint u3 = (uint)f2bf(a[6]) | ((uint)f2bf(a[7]) << 16);
    *(uint4*)(Ab0 + tid * 16) = make_uint4(u0, u1, u2, u3);
  }
  __syncthreads();

  for (int t = 0; t < NT; ++t) {
    const int k0 = t * 32;
    char* const Acur = (t & 1) ? Ab1 : Ab0;
    char* const Bcur = (t & 1) ? Bb1 : Bb0;
    char* const Anxt = (t & 1) ? Ab0 : Ab1;
    char* const Bnxt = (t & 1) ? Bb0 : Bb1;

    if (t + 1 < NT) {
      const int kn = k0 + 32;
#pragma unroll
      for (int i = 0; i < 8; i++) {
        const int s = i * 256 + tid;
        const int row = s >> 2, cch = s & 3;
        const unsigned short* g = Wt + (size_t)row * KPAD + kn + ((cch ^ ((row >> 1) & 3)) * 8);
        __builtin_amdgcn_global_load_lds(
            (const __attribute__((address_space(1))) void*)g,
            (__attribute__((address_space(3))) void*)(Bnxt + (i * 256 + wave * 64) * 16),
            16, 0, 0);
      }
      const int kb = kn + asrc;
      if (aok) {
        if (kb + 7 < IN_DIM) {
#pragma unroll
          for (int j = 0; j < 8; j++) a[j] = Arow[kb + j];
        } else {
#pragma unroll
          for (int j = 0; j < 8; j++) a[j] = (kb + j < IN_DIM) ? Arow[kb + j] : 0.f;
        }
      }
    }

    {
      __builtin_amdgcn_s_setprio(1);
      bf16x8 bv[8];
#pragma unroll
      for (int n = 0; n < 8; n++) {
        const int row = wave * 128 + n * 16 + fr;
        bv[n] = *(const bf16x8*)(Bcur + row * 64 + ((fq ^ ((row >> 1) & 3)) * 16));
      }
#pragma unroll
      for (int m = 0; m < 4; m++) {
        const int row = m * 16 + fr;
        bf16x8 av = *(const bf16x8*)(Acur + row * 64 + ((fq ^ ((row >> 1) & 3)) * 16));
#pragma unroll
        for (int n = 0; n < 8; n++)
          acc[m][n] = __builtin_amdgcn_mfma_f32_16x16x32_bf16(av, bv[n], acc[m][n], 0, 0, 0);
      }
      __builtin_amdgcn_s_setprio(0);
    }

    if (t + 1 < NT) {
      uint u0 = (uint)f2bf(a[0]) | ((uint)f2bf(a[1]) << 16);
      uint u1 = (uint)f2bf(a[2]) | ((uint)f2bf(a[3]) << 16);
      uint u2 = (uint)f2bf(a[4]) | ((uint)f2bf(a[5]) << 16);
      uint u3 = (uint)f2bf(a[6]) | ((uint)f2bf(a[7]) << 16);
      *(uint4*)(Anxt + tid * 16) = make_uint4(u0, u1, u2, u3);
    }
    __syncthreads();
  }

  // ---- C write (fp8)
#pragma unroll
  for (int m = 0; m < 4; m++) {
    const int r0 = brow + m * 16 + fq * 4;
#pragma unroll
    for (int n = 0; n < 8; n++) {
      const int col = wave * 128 + n * 16 + fr;
#pragma unroll
      for (int j = 0; j < 4; j++) {
        int r = r0 + j;
        if (r < N_NODES) H[(size_t)r * HCOLS + col] = f2fp8(acc[m][n][j]);
      }
    }
  }
}

// ------------------------------------- conv1 aggregation (pull, 16-deep fp8 gather)
__global__ void k_agg(const unsigned char* __restrict__ h,
                      const float* __restrict__ dinvL, const float* __restrict__ dinvG,
                      const int* __restrict__ rowL, const int* __restrict__ rowG,
                      const uint* __restrict__ erL, const uint* __restrict__ erG,
                      const float* __restrict__ biasL, const float* __restrict__ biasG,
                      unsigned short* __restrict__ xl) {
  const int br = blockIdx.y;
  const int node = blockIdx.x * 4 + (threadIdx.x >> 6);
  const int lane = threadIdx.x & 63;
  const float* __restrict__ dinv = br ? dinvG : dinvL;
  const int* __restrict__ rp = br ? rowG : rowL;
  const uint* __restrict__ er = br ? erG : erL;
  const float* __restrict__ bias = br ? biasG : biasL;
  const int off = br ? 256 : 0;
  const size_t lcol = off + lane * 4;

  float di = dinv[node];
  float w0 = di * di;  // self-loop norm
  uint u = *(const uint*)(h + (size_t)node * HCOLS + lcol);
  float a0 = w0 * __builtin_amdgcn_cvt_f32_fp8(u, 0);
  float a1 = w0 * __builtin_amdgcn_cvt_f32_fp8(u, 1);
  float a2 = w0 * __builtin_amdgcn_cvt_f32_fp8(u, 2);
  float a3 = w0 * __builtin_amdgcn_cvt_f32_fp8(u, 3);

  int e = rp[node];
  const int e1 = rp[node + 1];
  for (; e + 16 <= e1; e += 16) {
    uint r[16];
    uint v[16];
#pragma unroll
    for (int j = 0; j < 16; j++) r[j] = er[e + j];
#pragma unroll
    for (int j = 0; j < 16; j++)
      v[j] = *(const uint*)(h + (size_t)(r[j] & 0xffffu) * HCOLS + lcol);
#pragma unroll
    for (int j = 0; j < 16; j++) {
      float w = bf2f((unsigned short)(r[j] >> 16));
      a0 = fmaf(w, __builtin_amdgcn_cvt_f32_fp8(v[j], 0), a0);
      a1 = fmaf(w, __builtin_amdgcn_cvt_f32_fp8(v[j], 1), a1);
      a2 = fmaf(w, __builtin_amdgcn_cvt_f32_fp8(v[j], 2), a2);
      a3 = fmaf(w, __builtin_amdgcn_cvt_f32_fp8(v[j], 3), a3);
    }
  }
  for (; e + 4 <= e1; e += 4) {
    uint r[4];
    uint v[4];
#pragma unroll
    for (int j = 0; j < 4; j++) r[j] = er[e + j];
#pragma unroll
    for (int j = 0; j < 4; j++)
      v[j] = *(const uint*)(h + (size_t)(r[j] & 0xffffu) * HCOLS + lcol);
#pragma unroll
    for (int j = 0; j < 4; j++) {
      float w = bf2f((unsigned short)(r[j] >> 16));
      a0 = fmaf(w, __builtin_amdgcn_cvt_f32_fp8(v[j], 0), a0);
      a1 = fmaf(w, __builtin_amdgcn_cvt_f32_fp8(v[j], 1), a1);
      a2 = fmaf(w, __builtin_amdgcn_cvt_f32_fp8(v[j], 2), a2);
      a3 = fmaf(w, __builtin_amdgcn_cvt_f32_fp8(v[j], 3), a3);
    }
  }
  for (; e < e1; e++) {
    uint r = er[e];
    float w = bf2f((unsigned short)(r >> 16));
    uint v = *(const uint*)(h + (size_t)(r & 0xffffu) * HCOLS + lcol);
    a0 = fmaf(w, __builtin_amdgcn_cvt_f32_fp8(v, 0), a0);
    a1 = fmaf(w, __builtin_amdgcn_cvt_f32_fp8(v, 1), a1);
    a2 = fmaf(w, __builtin_amdgcn_cvt_f32_fp8(v, 2), a2);
    a3 = fmaf(w, __builtin_amdgcn_cvt_f32_fp8(v, 3), a3);
  }
  float4 b = *(const float4*)(bias + lane * 4);
  ushort4 o;
  o.x = f2bf(fmaxf(a0 + b.x, 0.f));
  o.y = f2bf(fmaxf(a1 + b.y, 0.f));
  o.z = f2bf(fmaxf(a2 + b.z, 0.f));
  o.w = f2bf(fmaxf(a3 + b.w, 0.f));
  *(ushort4*)(xl + (size_t)node * HCOLS + lcol) = o;
}

// --------------------------------- pool2: Spart[br][chunk][g][col] = c^T @ xl chunk
__launch_bounds__(256)
__global__ void k_pool2(const unsigned short* __restrict__ xl,
                        const float* __restrict__ cL, const float* __restrict__ cG,
                        float* __restrict__ Spart) {
  __shared__ float cs[64][64];  // 16 KB: 64 nodes x 64 graphs
  const int t = threadIdx.x;    // col 0..255
  const int chunk = blockIdx.x;
  const int br = blockIdx.y;
  const float* __restrict__ C = br ? cG : cL;
  const int xoff = br ? 256 : 0;
  const int n0 = chunk * PCH;
  float acc[64];
#pragma unroll
  for (int g = 0; g < 64; g++) acc[g] = 0.f;

  for (int tile = 0; tile < PCH; tile += 64) {
    const int base = n0 + tile;
    __syncthreads();
#pragma unroll
    for (int i = 0; i < 16; i++) {
      int idx = i * 256 + t;  // 0..4095
      int nn = idx >> 6, gg = idx & 63;
      int node = base + nn;
      cs[nn][gg] = (node < N_NODES) ? C[(size_t)node * 64 + gg] : 0.f;
    }
    __syncthreads();
    for (int nn = 0; nn < 64; nn++) {
      int node = base + nn;
      float v = (node < N_NODES) ? bf2f(xl[(size_t)node * HCOLS + xoff + t]) : 0.f;
#pragma unroll
      for (int g4 = 0; g4 < 16; g4++) {
        float4 cv = *(const float4*)&cs[nn][g4 * 4];
        acc[g4 * 4 + 0] = fmaf(cv.x, v, acc[g4 * 4 + 0]);
        acc[g4 * 4 + 1] = fmaf(cv.y, v, acc[g4 * 4 + 1]);
        acc[g4 * 4 + 2] = fmaf(cv.z, v, acc[g4 * 4 + 2]);
        acc[g4 * 4 + 3] = fmaf(cv.w, v, acc[g4 * 4 + 3]);
      }
    }
  }
  float* sp = Spart + ((size_t)br * NCHUNK + chunk) * 16384 + t;
#pragma unroll
  for (int g = 0; g < 64; g++) sp[g * 256] = acc[g];
}

__global__ void k_pool_reduce(const float* __restrict__ Spart, float* __restrict__ S) {
  int i = blockIdx.x * blockDim.x + threadIdx.x;  // 0..32767
  if (i >= 2 * 16384) return;
  int br = i >> 14, idx = i & 16383;
  const float* p = Spart + (size_t)br * NCHUNK * 16384 + idx;
  float s = 0.f;
  for (int ch = 0; ch < NCHUNK; ch++) s += p[(size_t)ch * 16384];
  S[i] = s;
}

// ---------------------------------------------------------------- final fuse
__global__ void k_final(const float* __restrict__ S,  // [2][64][256]
                        const float* __restrict__ Wl2, const float* __restrict__ bl2,
                        const float* __restrict__ Wg2, const float* __restrict__ bg2,
                        const float* __restrict__ Wf, const float* __restrict__ bf,
                        const int* __restrict__ start, float* __restrict__ out) {
  __shared__ float pl[OUT_DIM], pg[OUT_DIM];
  int g = blockIdx.x, t = threadIdx.x;
  float invc = 1.0f / fmaxf((float)(start[g + 1] - start[g]), 1.0f);
  const float* Sl = S + (size_t)g * HIDDEN;
  const float* Sg = S + (size_t)N_GRAPHS * HIDDEN + (size_t)g * HIDDEN;
  float al = 0.f, ag = 0.f;
  for (int k = 0; k < HIDDEN; k++) {
    al = fmaf(Sl[k], Wl2[k * OUT_DIM + t], al);
    ag = fmaf(Sg[k], Wg2[k * OUT_DIM + t], ag);
  }
  pl[t] = al * invc + bl2[t];
  pg[t] = ag * invc + bg2[t];
  __syncthreads();
  float o = bf[t];
  for (int j = 0; j < OUT_DIM; j++) {
    o = fmaf(pl[j], Wf[j * OUT_DIM + t], o);
    o = fmaf(pg[j], Wf[(OUT_DIM + j) * OUT_DIM + t], o);
  }
  out[(size_t)g * OUT_DIM + t] = fmaxf(o, 0.f);
}

// ---------------------------------------------------------------- launch
extern "C" void kernel_launch(void* const* d_in, const int* in_sizes, int n_in,
                              void* d_out, int out_size, void* d_ws, size_t ws_size,
                              hipStream_t stream) {
  const float* x = (const float*)d_in[0];
  const int* el = (const int*)d_in[1];
  const int* eg = (const int*)d_in[2];
  const int* batch = (const int*)d_in[3];
  const float* Wl1 = (const float*)d_in[4];
  const float* bl1 = (const float*)d_in[5];
  const float* Wl2 = (const float*)d_in[6];
  const float* bl2 = (const float*)d_in[7];
  const float* Wg1 = (const float*)d_in[8];
  const float* bg1 = (const float*)d_in[9];
  const float* Wg2 = (const float*)d_in[10];
  const float* bg2 = (const float*)d_in[11];
  const float* Wf = (const float*)d_in[12];
  const float* bf = (const float*)d_in[13];
  float* out = (float*)d_out;
  char* ws = (char*)d_ws;

  // ---- workspace layout (256B aligned). Zero-region (c matrices) first.
  const size_t NPAD = 200192;  // 50000*4 padded
  size_t off = 0;
  float* c_l = (float*)(ws + off); off += (size_t)N_NODES * 64 * 4;  // 12.8 MB
  float* c_g = (float*)(ws + off); off += (size_t)N_NODES * 64 * 4;  // 12.8 MB
  const size_t zero_bytes = off;
  int* start = (int*)(ws + off); off += 512;    // 65 ints (start[64] is used!)
  float* S = (float*)(ws + off); off += (size_t)2 * N_GRAPHS * HIDDEN * 4;
  int* deg_l = (int*)(ws + off); off += NPAD;
  int* deg_g = (int*)(ws + off); off += NPAD;
  float* dinv_l = (float*)(ws + off); off += NPAD;
  float* dinv_g = (float*)(ws + off); off += NPAD;
  int* row_l = (int*)(ws + off); off += NPAD;
  int* row_g = (int*)(ws + off); off += NPAD;
  int* partL = (int*)(ws + off); off += (size_t)SL_L * 4 * QUARTER * 4;  // 12.85 MB
  int* partG = (int*)(ws + off); off += (size_t)SL_G * 4 * QUARTER * 4;  // 25.7 MB
  uint* er_l = (uint*)(ws + off); off += (size_t)EDGES_L * 4;   // 3.2 MB
  uint* er_g = (uint*)(ws + off); off += (size_t)EDGES_G * 4;   // 6.4 MB
  unsigned short* Wt = (unsigned short*)(ws + off); off += (size_t)HCOLS * KPAD * 2;  // 2.2 MB
  unsigned char* h = (unsigned char*)(ws + off); off += (size_t)N_NODES * HCOLS;        // 25.6 MB
  unsigned short* xl = (unsigned short*)(ws + off); off += (size_t)N_NODES * HCOLS * 2; // 51.2 MB
  // Spart (2*98*16384*4 = 12.8MB) aliases partL (12.85MB, dead after fused kernel).
  float* Spart = (float*)partL;

  const int* srcL = el;
  const int* dstL = el + EDGES_L;
  const int* srcG = eg;
  const int* dstG = eg + EDGES_G;

  hipMemsetAsync(ws, 0, zero_bytes, stream);

  k_cvt_w<<<(HCOLS * KPAD + 255) / 256, 256, 0, stream>>>(Wl1, Wg1, Wt);

  // preprocessing (atomic-free)
  k_hist<<<HBLOCKS, 256, 0, stream>>>(dstL, dstG, partL, partG);
  k_prefix<<<(8 * QUARTER + 255) / 256, 256, 0, stream>>>(partL, partG, batch, deg_l, deg_g,
                                                          dinv_l, dinv_g, c_l, c_g);
  k_scan1<<<51, 1024, 0, stream>>>(deg_l, deg_g, row_l, row_g, batch, start);

  // FUSED GEMM (blocks 0..781) + scatter (blocks 782..1549), index-ordered
  k_gemm_scat<<<NGB + HBLOCKS, 256, 0, stream>>>(x, Wt, h, srcL, dstL, srcG, dstG,
                                                 partL, partG, row_l, row_g, dinv_l, dinv_g,
                                                 batch, er_l, er_g, c_l, c_g);

  // conv1 aggregation: both branches, 16-deep unrolled fp8 gather
  dim3 agrid(N_NODES / 4, 2);
  k_agg<<<agrid, 256, 0, stream>>>(h, dinv_l, dinv_g, row_l, row_g, er_l, er_g, bl1, bg1, xl);

  // pool2 (PCH=512 -> 98 chunks; Spart aliased over dead partL)
  dim3 pgrid(NCHUNK, 2);
  k_pool2<<<pgrid, 256, 0, stream>>>(xl, c_l, c_g, Spart);
  k_pool_reduce<<<(2 * 16384 + 255) / 256, 256, 0, stream>>>(Spart, S);

  k_final<<<N_GRAPHS, OUT_DIM, 0, stream>>>(S, Wl2, bl2, Wg2, bg2, Wf, bf, start, out);
}

// Round 23
// 849.249 us; speedup vs baseline: 1.1329x; 1.1329x over previous
//
#include <hip/hip_runtime.h>
#include <hip/hip_bf16.h>
#include <cstdint>
#include <cstddef>

// GCNEncoder: two-branch GCN on MI355X.
// Round 23: exact round-20 configuration (850us session best). Round-22's
// PCH=512 regressed pool2 (196 blocks < 256 CUs -> idle CUs); PCH=256 restored.
// Pipeline:
//   1) memset c_l/c_g (25.6MB)
//   2) cvt W -> bf16 Wt[512][2112]
//   3) k_hist -> k_prefix -> k_scan1(+bounds)
//   4) k_gemm_scat: GEMM blocks [0,782) (fp8 C-write) + scatter blocks
//      [782,1550) (LDS-rank sort -> packed er + fused c atomicAdd)
//   5) k_agg: CSR pull, wave/node, 16-deep fp8 gather
//   6) k_pool2 (PCH=256): Spart = c^T @ xl; k_pool_reduce -> S
//   7) k_final: (S@W2)/cnt + b2, concat, @W_fuse + b_fuse, relu -> out[64x128]

#define N_NODES 50000
#define N_GRAPHS 64
#define IN_DIM 2063
#define HIDDEN 256
#define OUT_DIM 128
#define EDGES_L 800000
#define EDGES_G 1600000
#define HCOLS 512   // [local 0..255 | global 256..511]
#define KPAD 2112   // 66 * 32
#define MPAD 50048  // 782 * 64
#define GBM 64      // GEMM M-tile
#define NGB (MPAD / GBM)                         // 782 GEMM blocks
#define NT (KPAD / 32)                           // 66 K-steps
#define PCH 256                                  // nodes per pool2 chunk
#define NCHUNK ((N_NODES + PCH - 1) / PCH)       // 196

// histogram geometry
#define QUARTER 12544                 // 4*12544 = 50176 >= N_NODES
#define SL_L 64                       // slices (L): 800000/64  = 12500 edges
#define SL_G 128                      // slices (G): 1600000/128 = 12500 edges
#define EPS 12500                     // edges per slice
#define HBLOCKS (4 * (SL_L + SL_G))   // 768 scatter blocks

typedef __attribute__((ext_vector_type(8))) __bf16 bf16x8;
typedef __attribute__((ext_vector_type(4))) float f32x4;

__device__ __forceinline__ float bf2f(unsigned short u) {
  union { unsigned int i; float f; } c; c.i = ((unsigned int)u) << 16; return c.f;
}
__device__ __forceinline__ unsigned short f2bf(float f) {
  __hip_bfloat16 h = __float2bfloat16(f);
  return *reinterpret_cast<unsigned short*>(&h);
}
__device__ __forceinline__ unsigned char f2fp8(float f) {
  return (unsigned char)(__builtin_amdgcn_cvt_pk_fp8_f32(f, f, 0, 0) & 0xff);
}

// ---------------------------------------------------------------- converts
__global__ void k_cvt_w(const float* __restrict__ Wl, const float* __restrict__ Wg,
                        unsigned short* __restrict__ Wt) {
  int i = blockIdx.x * blockDim.x + threadIdx.x;
  if (i >= HCOLS * KPAD) return;
  int n = i / KPAD;
  int k = i - n * KPAD;
  float v = 0.f;
  if (k < IN_DIM) {
    v = (n < HIDDEN) ? Wl[(size_t)k * HIDDEN + n] : Wg[(size_t)k * HIDDEN + (n - HIDDEN)];
  }
  Wt[(size_t)n * KPAD + k] = f2bf(v);
}

// ---------------- hist: LDS-private degree histogram, partials to global (no atomics)
__launch_bounds__(256)
__global__ void k_hist(const int* __restrict__ dstL, const int* __restrict__ dstG,
                       int* __restrict__ partL, int* __restrict__ partG) {
  __shared__ int hist[QUARTER];  // 50176 B
  const int i = blockIdx.x;
  const int* __restrict__ dst;
  int slice, q;
  int* __restrict__ part;
  if (i < 4 * SL_L) {
    slice = i >> 2; q = i & 3;
    dst = dstL;
    part = partL + (size_t)(slice * 4 + q) * QUARTER;
  } else {
    int j = i - 4 * SL_L;
    slice = j >> 2; q = j & 3;
    dst = dstG;
    part = partG + (size_t)(slice * 4 + q) * QUARTER;
  }
  for (int t = threadIdx.x; t < QUARTER; t += 256) hist[t] = 0;
  __syncthreads();
  const int e0 = slice * EPS;
  const int qbase = q * QUARTER;
  for (int e = e0 + threadIdx.x; e < e0 + EPS; e += 256) {
    int d = dst[e] - qbase;
    if ((unsigned)d < QUARTER) atomicAdd(&hist[d], 1);
  }
  __syncthreads();
  for (int t = threadIdx.x; t < QUARTER; t += 256) part[t] = hist[t];
}

// -------- prefix: per-(branch,node) scan over slices; emits deg/dinv/self-c; rewrites
// partials in place to exclusive per-slice offsets.
__global__ void k_prefix(int* __restrict__ partL, int* __restrict__ partG,
                         const int* __restrict__ batch, int* __restrict__ degL,
                         int* __restrict__ degG, float* __restrict__ dinvL,
                         float* __restrict__ dinvG, float* __restrict__ cL,
                         float* __restrict__ cG) {
  int t = blockIdx.x * blockDim.x + threadIdx.x;  // 0 .. 2*4*QUARTER-1
  if (t >= 8 * QUARTER) return;
  const int b = t / (4 * QUARTER);           // 0=L, 1=G
  const int n = t - b * 4 * QUARTER;         // node 0..50175
  const int q = n / QUARTER, loc = n - q * QUARTER;
  const int NS = b ? SL_G : SL_L;
  int* p = (b ? partG : partL) + (size_t)q * QUARTER + loc;
  int run = 0;
  for (int s = 0; s < NS; s++) {
    int* pp = p + (size_t)s * 4 * QUARTER;
    int v = *pp;
    *pp = run;
    run += v;
  }
  if (n < N_NODES) {
    float d = 1.0f / sqrtf((float)(run + 1));
    if (b == 0) {
      degL[n] = run; dinvL[n] = d; cL[(size_t)n * 64 + batch[n]] = d * d;
    } else {
      degG[n] = run; dinvG[n] = d; cG[(size_t)n * 64 + batch[n]] = d * d;
    }
  }
}

// ------- scan1: blocks 0,1 = exclusive degree scan -> row_ptr; blocks 2..50 = bounds
__global__ void k_scan1(const int* __restrict__ degL, const int* __restrict__ degG,
                        int* __restrict__ rowL, int* __restrict__ rowG,
                        const int* __restrict__ batch, int* __restrict__ start) {
  if (blockIdx.x >= 2) {
    int n = (blockIdx.x - 2) * 1024 + threadIdx.x;
    if (n >= N_NODES) return;
    int bn = batch[n];
    int bp = n ? batch[n - 1] : -1;
    for (int g = bp + 1; g <= bn; g++) start[g] = n;
    if (n == N_NODES - 1)
      for (int g = bn + 1; g <= N_GRAPHS; g++) start[g] = N_NODES;
    return;
  }
  __shared__ int part[1024];
  const int t = threadIdx.x;
  const int* __restrict__ deg = blockIdx.x ? degG : degL;
  int* __restrict__ row = blockIdx.x ? rowG : rowL;
  const int c0 = t * 49;  // 49*1024 = 50176 >= 50000
  int s = 0;
  for (int j = 0; j < 49; j++) {
    int idx = c0 + j;
    s += (idx < N_NODES) ? deg[idx] : 0;
  }
  part[t] = s;
  __syncthreads();
  for (int ofs = 1; ofs < 1024; ofs <<= 1) {
    int v = (t >= ofs) ? part[t - ofs] : 0;
    __syncthreads();
    part[t] += v;
    __syncthreads();
  }
  int run = (t > 0) ? part[t - 1] : 0;
  for (int j = 0; j < 49; j++) {
    int idx = c0 + j;
    if (idx < N_NODES) { row[idx] = run; run += deg[idx]; }
  }
  if (t == 1023) row[N_NODES] = part[1023];
}

// ------------------- FUSED: GEMM blocks [0,NGB) then scatter blocks [NGB,+HBLOCKS)
__launch_bounds__(256)
__global__ void k_gemm_scat(const float* __restrict__ X,
                            const unsigned short* __restrict__ Wt,
                            unsigned char* __restrict__ H,
                            const int* __restrict__ srcL, const int* __restrict__ dstL,
                            const int* __restrict__ srcG, const int* __restrict__ dstG,
                            const int* __restrict__ partL, const int* __restrict__ partG,
                            const int* __restrict__ rowL, const int* __restrict__ rowG,
                            const float* __restrict__ dinvL, const float* __restrict__ dinvG,
                            const int* __restrict__ batch, uint* __restrict__ erL,
                            uint* __restrict__ erG, float* __restrict__ cL,
                            float* __restrict__ cG) {
  __shared__ __align__(16) char lds[2 * 4096 + 2 * 32768];  // 72KB (role union)

  if (blockIdx.x >= NGB) {
    // -------- scatter role: packed er (src:16 | bf16 norm:16) + c atomicAdd --------
    int* hist = (int*)lds;
    const int i = blockIdx.x - NGB;
    const int *src, *dst, *part, *row;
    const float* dinv;
    uint* er;
    float* c;
    int slice, q;
    if (i < 4 * SL_L) {
      slice = i >> 2; q = i & 3;
      src = srcL; dst = dstL; row = rowL; dinv = dinvL; er = erL; c = cL;
      part = partL + (size_t)(slice * 4 + q) * QUARTER;
    } else {
      int j = i - 4 * SL_L;
      slice = j >> 2; q = j & 3;
      src = srcG; dst = dstG; row = rowG; dinv = dinvG; er = erG; c = cG;
      part = partG + (size_t)(slice * 4 + q) * QUARTER;
    }
    for (int t = threadIdx.x; t < QUARTER; t += 256) hist[t] = 0;
    __syncthreads();
    const int e0 = slice * EPS;
    const int qbase = q * QUARTER;
    for (int e = e0 + threadIdx.x; e < e0 + EPS; e += 256) {
      int d = dst[e];
      int loc = d - qbase;
      if ((unsigned)loc < QUARTER) {
        int s = src[e];
        int rank = atomicAdd(&hist[loc], 1);  // LDS atomic
        int pos = row[d] + part[loc] + rank;
        float nrm = dinv[s] * dinv[d];
        er[pos] = (uint)s | ((uint)f2bf(nrm) << 16);
        atomicAdd(&c[(size_t)s * 64 + batch[d]], nrm);
      }
    }
    return;
  }

  // ---------------- GEMM role ----------------
  char* const Ab0 = lds;
  char* const Ab1 = lds + 4096;
  char* const Bb0 = lds + 8192;
  char* const Bb1 = lds + 8192 + 32768;
  const int tid = threadIdx.x;
  const int lane = tid & 63;
  const int wave = tid >> 6;
  const int brow = blockIdx.x * GBM;

  const int ar = tid >> 2;
  const int ach = tid & 3;
  const int askew = (ar >> 1) & 3;
  const int asrc = (ach ^ askew) * 8;
  const int arow_g = brow + ar;
  const bool aok = arow_g < N_NODES;
  const float* __restrict__ Arow = X + (size_t)arow_g * IN_DIM;

  const int fr = lane & 15;
  const int fq = lane >> 4;

  f32x4 acc[4][8];
  const f32x4 zero = {0.f, 0.f, 0.f, 0.f};
#pragma unroll
  for (int m = 0; m < 4; m++)
#pragma unroll
    for (int n = 0; n < 8; n++) acc[m][n] = zero;

  // prologue: B(0) into Bb0; A(0) regs -> pack -> Ab0
#pragma unroll
  for (int i = 0; i < 8; i++) {
    const int s = i * 256 + tid;
    const int row = s >> 2, cch = s & 3;
    const unsigned short* g = Wt + (size_t)row * KPAD + ((cch ^ ((row >> 1) & 3)) * 8);
    __builtin_amdgcn_global_load_lds(
        (const __attribute__((address_space(1))) void*)g,
        (__attribute__((address_space(3))) void*)(Bb0 + (i * 256 + wave * 64) * 16),
        16, 0, 0);
  }
  float a[8];
#pragma unroll
  for (int j = 0; j < 8; j++) a[j] = aok ? Arow[asrc + j] : 0.f;
  {
    uint u0 = (uint)f2bf(a[0]) | ((uint)f2bf(a[1]) << 16);
    uint u1 = (uint)f2bf(a[2]) | ((uint)f2bf(a[3]) << 16);
    uint u2 = (uint)f2bf(a[4]) | ((uint)f2bf(a[5]) << 16);
    uint u3 = (uint)f2bf(a[6]) | ((uint)f2bf(a[7]) << 16);
    *(uint4*)(Ab0 + tid * 16) = make_uint4(u0, u1, u2, u3);
  }
  __syncthreads();

  for (int t = 0; t < NT; ++t) {
    const int k0 = t * 32;
    char* const Acur = (t & 1) ? Ab1 : Ab0;
    char* const Bcur = (t & 1) ? Bb1 : Bb0;
    char* const Anxt = (t & 1) ? Ab0 : Ab1;
    char* const Bnxt = (t & 1) ? Bb0 : Bb1;

    if (t + 1 < NT) {
      const int kn = k0 + 32;
#pragma unroll
      for (int i = 0; i < 8; i++) {
        const int s = i * 256 + tid;
        const int row = s >> 2, cch = s & 3;
        const unsigned short* g = Wt + (size_t)row * KPAD + kn + ((cch ^ ((row >> 1) & 3)) * 8);
        __builtin_amdgcn_global_load_lds(
            (const __attribute__((address_space(1))) void*)g,
            (__attribute__((address_space(3))) void*)(Bnxt + (i * 256 + wave * 64) * 16),
            16, 0, 0);
      }
      const int kb = kn + asrc;
      if (aok) {
        if (kb + 7 < IN_DIM) {
#pragma unroll
          for (int j = 0; j < 8; j++) a[j] = Arow[kb + j];
        } else {
#pragma unroll
          for (int j = 0; j < 8; j++) a[j] = (kb + j < IN_DIM) ? Arow[kb + j] : 0.f;
        }
      }
    }

    {
      __builtin_amdgcn_s_setprio(1);
      bf16x8 bv[8];
#pragma unroll
      for (int n = 0; n < 8; n++) {
        const int row = wave * 128 + n * 16 + fr;
        bv[n] = *(const bf16x8*)(Bcur + row * 64 + ((fq ^ ((row >> 1) & 3)) * 16));
      }
#pragma unroll
      for (int m = 0; m < 4; m++) {
        const int row = m * 16 + fr;
        bf16x8 av = *(const bf16x8*)(Acur + row * 64 + ((fq ^ ((row >> 1) & 3)) * 16));
#pragma unroll
        for (int n = 0; n < 8; n++)
          acc[m][n] = __builtin_amdgcn_mfma_f32_16x16x32_bf16(av, bv[n], acc[m][n], 0, 0, 0);
      }
      __builtin_amdgcn_s_setprio(0);
    }

    if (t + 1 < NT) {
      uint u0 = (uint)f2bf(a[0]) | ((uint)f2bf(a[1]) << 16);
      uint u1 = (uint)f2bf(a[2]) | ((uint)f2bf(a[3]) << 16);
      uint u2 = (uint)f2bf(a[4]) | ((uint)f2bf(a[5]) << 16);
      uint u3 = (uint)f2bf(a[6]) | ((uint)f2bf(a[7]) << 16);
      *(uint4*)(Anxt + tid * 16) = make_uint4(u0, u1, u2, u3);
    }
    __syncthreads();
  }

  // ---- C write (fp8)
#pragma unroll
  for (int m = 0; m < 4; m++) {
    const int r0 = brow + m * 16 + fq * 4;
#pragma unroll
    for (int n = 0; n < 8; n++) {
      const int col = wave * 128 + n * 16 + fr;
#pragma unroll
      for (int j = 0; j < 4; j++) {
        int r = r0 + j;
        if (r < N_NODES) H[(size_t)r * HCOLS + col] = f2fp8(acc[m][n][j]);
      }
    }
  }
}

// ------------------------------------- conv1 aggregation (pull, 16-deep fp8 gather)
__global__ void k_agg(const unsigned char* __restrict__ h,
                      const float* __restrict__ dinvL, const float* __restrict__ dinvG,
                      const int* __restrict__ rowL, const int* __restrict__ rowG,
                      const uint* __restrict__ erL, const uint* __restrict__ erG,
                      const float* __restrict__ biasL, const float* __restrict__ biasG,
                      unsigned short* __restrict__ xl) {
  const int br = blockIdx.y;
  const int node = blockIdx.x * 4 + (threadIdx.x >> 6);
  const int lane = threadIdx.x & 63;
  const float* __restrict__ dinv = br ? dinvG : dinvL;
  const int* __restrict__ rp = br ? rowG : rowL;
  const uint* __restrict__ er = br ? erG : erL;
  const float* __restrict__ bias = br ? biasG : biasL;
  const int off = br ? 256 : 0;
  const size_t lcol = off + lane * 4;

  float di = dinv[node];
  float w0 = di * di;  // self-loop norm
  uint u = *(const uint*)(h + (size_t)node * HCOLS + lcol);
  float a0 = w0 * __builtin_amdgcn_cvt_f32_fp8(u, 0);
  float a1 = w0 * __builtin_amdgcn_cvt_f32_fp8(u, 1);
  float a2 = w0 * __builtin_amdgcn_cvt_f32_fp8(u, 2);
  float a3 = w0 * __builtin_amdgcn_cvt_f32_fp8(u, 3);

  int e = rp[node];
  const int e1 = rp[node + 1];
  for (; e + 16 <= e1; e += 16) {
    uint r[16];
    uint v[16];
#pragma unroll
    for (int j = 0; j < 16; j++) r[j] = er[e + j];
#pragma unroll
    for (int j = 0; j < 16; j++)
      v[j] = *(const uint*)(h + (size_t)(r[j] & 0xffffu) * HCOLS + lcol);
#pragma unroll
    for (int j = 0; j < 16; j++) {
      float w = bf2f((unsigned short)(r[j] >> 16));
      a0 = fmaf(w, __builtin_amdgcn_cvt_f32_fp8(v[j], 0), a0);
      a1 = fmaf(w, __builtin_amdgcn_cvt_f32_fp8(v[j], 1), a1);
      a2 = fmaf(w, __builtin_amdgcn_cvt_f32_fp8(v[j], 2), a2);
      a3 = fmaf(w, __builtin_amdgcn_cvt_f32_fp8(v[j], 3), a3);
    }
  }
  for (; e + 4 <= e1; e += 4) {
    uint r[4];
    uint v[4];
#pragma unroll
    for (int j = 0; j < 4; j++) r[j] = er[e + j];
#pragma unroll
    for (int j = 0; j < 4; j++)
      v[j] = *(const uint*)(h + (size_t)(r[j] & 0xffffu) * HCOLS + lcol);
#pragma unroll
    for (int j = 0; j < 4; j++) {
      float w = bf2f((unsigned short)(r[j] >> 16));
      a0 = fmaf(w, __builtin_amdgcn_cvt_f32_fp8(v[j], 0), a0);
      a1 = fmaf(w, __builtin_amdgcn_cvt_f32_fp8(v[j], 1), a1);
      a2 = fmaf(w, __builtin_amdgcn_cvt_f32_fp8(v[j], 2), a2);
      a3 = fmaf(w, __builtin_amdgcn_cvt_f32_fp8(v[j], 3), a3);
    }
  }
  for (; e < e1; e++) {
    uint r = er[e];
    float w = bf2f((unsigned short)(r >> 16));
    uint v = *(const uint*)(h + (size_t)(r & 0xffffu) * HCOLS + lcol);
    a0 = fmaf(w, __builtin_amdgcn_cvt_f32_fp8(v, 0), a0);
    a1 = fmaf(w, __builtin_amdgcn_cvt_f32_fp8(v, 1), a1);
    a2 = fmaf(w, __builtin_amdgcn_cvt_f32_fp8(v, 2), a2);
    a3 = fmaf(w, __builtin_amdgcn_cvt_f32_fp8(v, 3), a3);
  }
  float4 b = *(const float4*)(bias + lane * 4);
  ushort4 o;
  o.x = f2bf(fmaxf(a0 + b.x, 0.f));
  o.y = f2bf(fmaxf(a1 + b.y, 0.f));
  o.z = f2bf(fmaxf(a2 + b.z, 0.f));
  o.w = f2bf(fmaxf(a3 + b.w, 0.f));
  *(ushort4*)(xl + (size_t)node * HCOLS + lcol) = o;
}

// --------------------------------- pool2: Spart[br][chunk][g][col] = c^T @ xl chunk
__launch_bounds__(256)
__global__ void k_pool2(const unsigned short* __restrict__ xl,
                        const float* __restrict__ cL, const float* __restrict__ cG,
                        float* __restrict__ Spart) {
  __shared__ float cs[64][64];  // 16 KB: 64 nodes x 64 graphs
  const int t = threadIdx.x;    // col 0..255
  const int chunk = blockIdx.x;
  const int br = blockIdx.y;
  const float* __restrict__ C = br ? cG : cL;
  const int xoff = br ? 256 : 0;
  const int n0 = chunk * PCH;
  float acc[64];
#pragma unroll
  for (int g = 0; g < 64; g++) acc[g] = 0.f;

  for (int tile = 0; tile < PCH; tile += 64) {
    const int base = n0 + tile;
    __syncthreads();
#pragma unroll
    for (int i = 0; i < 16; i++) {
      int idx = i * 256 + t;  // 0..4095
      int nn = idx >> 6, gg = idx & 63;
      int node = base + nn;
      cs[nn][gg] = (node < N_NODES) ? C[(size_t)node * 64 + gg] : 0.f;
    }
    __syncthreads();
    for (int nn = 0; nn < 64; nn++) {
      int node = base + nn;
      float v = (node < N_NODES) ? bf2f(xl[(size_t)node * HCOLS + xoff + t]) : 0.f;
#pragma unroll
      for (int g4 = 0; g4 < 16; g4++) {
        float4 cv = *(const float4*)&cs[nn][g4 * 4];
        acc[g4 * 4 + 0] = fmaf(cv.x, v, acc[g4 * 4 + 0]);
        acc[g4 * 4 + 1] = fmaf(cv.y, v, acc[g4 * 4 + 1]);
        acc[g4 * 4 + 2] = fmaf(cv.z, v, acc[g4 * 4 + 2]);
        acc[g4 * 4 + 3] = fmaf(cv.w, v, acc[g4 * 4 + 3]);
      }
    }
  }
  float* sp = Spart + ((size_t)br * NCHUNK + chunk) * 16384 + t;
#pragma unroll
  for (int g = 0; g < 64; g++) sp[g * 256] = acc[g];
}

__global__ void k_pool_reduce(const float* __restrict__ Spart, float* __restrict__ S) {
  int i = blockIdx.x * blockDim.x + threadIdx.x;  // 0..32767
  if (i >= 2 * 16384) return;
  int br = i >> 14, idx = i & 16383;
  const float* p = Spart + (size_t)br * NCHUNK * 16384 + idx;
  float s = 0.f;
  for (int ch = 0; ch < NCHUNK; ch++) s += p[(size_t)ch * 16384];
  S[i] = s;
}

// ---------------------------------------------------------------- final fuse
__global__ void k_final(const float* __restrict__ S,  // [2][64][256]
                        const float* __restrict__ Wl2, const float* __restrict__ bl2,
                        const float* __restrict__ Wg2, const float* __restrict__ bg2,
                        const float* __restrict__ Wf, const float* __restrict__ bf,
                        const int* __restrict__ start, float* __restrict__ out) {
  __shared__ float pl[OUT_DIM], pg[OUT_DIM];
  int g = blockIdx.x, t = threadIdx.x;
  float invc = 1.0f / fmaxf((float)(start[g + 1] - start[g]), 1.0f);
  const float* Sl = S + (size_t)g * HIDDEN;
  const float* Sg = S + (size_t)N_GRAPHS * HIDDEN + (size_t)g * HIDDEN;
  float al = 0.f, ag = 0.f;
  for (int k = 0; k < HIDDEN; k++) {
    al = fmaf(Sl[k], Wl2[k * OUT_DIM + t], al);
    ag = fmaf(Sg[k], Wg2[k * OUT_DIM + t], ag);
  }
  pl[t] = al * invc + bl2[t];
  pg[t] = ag * invc + bg2[t];
  __syncthreads();
  float o = bf[t];
  for (int j = 0; j < OUT_DIM; j++) {
    o = fmaf(pl[j], Wf[j * OUT_DIM + t], o);
    o = fmaf(pg[j], Wf[(OUT_DIM + j) * OUT_DIM + t], o);
  }
  out[(size_t)g * OUT_DIM + t] = fmaxf(o, 0.f);
}

// ---------------------------------------------------------------- launch
extern "C" void kernel_launch(void* const* d_in, const int* in_sizes, int n_in,
                              void* d_out, int out_size, void* d_ws, size_t ws_size,
                              hipStream_t stream) {
  const float* x = (const float*)d_in[0];
  const int* el = (const int*)d_in[1];
  const int* eg = (const int*)d_in[2];
  const int* batch = (const int*)d_in[3];
  const float* Wl1 = (const float*)d_in[4];
  const float* bl1 = (const float*)d_in[5];
  const float* Wl2 = (const float*)d_in[6];
  const float* bl2 = (const float*)d_in[7];
  const float* Wg1 = (const float*)d_in[8];
  const float* bg1 = (const float*)d_in[9];
  const float* Wg2 = (const float*)d_in[10];
  const float* bg2 = (const float*)d_in[11];
  const float* Wf = (const float*)d_in[12];
  const float* bf = (const float*)d_in[13];
  float* out = (float*)d_out;
  char* ws = (char*)d_ws;

  // ---- workspace layout (256B aligned). Zero-region (c matrices) first.
  const size_t NPAD = 200192;  // 50000*4 padded
  size_t off = 0;
  float* c_l = (float*)(ws + off); off += (size_t)N_NODES * 64 * 4;  // 12.8 MB
  float* c_g = (float*)(ws + off); off += (size_t)N_NODES * 64 * 4;  // 12.8 MB
  const size_t zero_bytes = off;
  int* start = (int*)(ws + off); off += 512;    // 65 ints (start[64] is used!)
  float* S = (float*)(ws + off); off += (size_t)2 * N_GRAPHS * HIDDEN * 4;
  int* deg_l = (int*)(ws + off); off += NPAD;
  int* deg_g = (int*)(ws + off); off += NPAD;
  float* dinv_l = (float*)(ws + off); off += NPAD;
  float* dinv_g = (float*)(ws + off); off += NPAD;
  int* row_l = (int*)(ws + off); off += NPAD;
  int* row_g = (int*)(ws + off); off += NPAD;
  int* partL = (int*)(ws + off); off += (size_t)SL_L * 4 * QUARTER * 4;  // 12.85 MB
  int* partG = (int*)(ws + off); off += (size_t)SL_G * 4 * QUARTER * 4;  // 25.7 MB
  uint* er_l = (uint*)(ws + off); off += (size_t)EDGES_L * 4;   // 3.2 MB
  uint* er_g = (uint*)(ws + off); off += (size_t)EDGES_G * 4;   // 6.4 MB
  unsigned short* Wt = (unsigned short*)(ws + off); off += (size_t)HCOLS * KPAD * 2;  // 2.2 MB
  unsigned char* h = (unsigned char*)(ws + off); off += (size_t)N_NODES * HCOLS;        // 25.6 MB
  unsigned short* xl = (unsigned short*)(ws + off); off += (size_t)N_NODES * HCOLS * 2; // 51.2 MB
  // Spart (2*196*16384*4 = 25.7MB) aliases partL+partG (38.5MB, dead after fused kernel).
  float* Spart = (float*)partL;

  const int* srcL = el;
  const int* dstL = el + EDGES_L;
  const int* srcG = eg;
  const int* dstG = eg + EDGES_G;

  hipMemsetAsync(ws, 0, zero_bytes, stream);

  k_cvt_w<<<(HCOLS * KPAD + 255) / 256, 256, 0, stream>>>(Wl1, Wg1, Wt);

  // preprocessing (atomic-free)
  k_hist<<<HBLOCKS, 256, 0, stream>>>(dstL, dstG, partL, partG);
  k_prefix<<<(8 * QUARTER + 255) / 256, 256, 0, stream>>>(partL, partG, batch, deg_l, deg_g,
                                                          dinv_l, dinv_g, c_l, c_g);
  k_scan1<<<51, 1024, 0, stream>>>(deg_l, deg_g, row_l, row_g, batch, start);

  // FUSED GEMM (blocks 0..781) + scatter (blocks 782..1549), index-ordered
  k_gemm_scat<<<NGB + HBLOCKS, 256, 0, stream>>>(x, Wt, h, srcL, dstL, srcG, dstG,
                                                 partL, partG, row_l, row_g, dinv_l, dinv_g,
                                                 batch, er_l, er_g, c_l, c_g);

  // conv1 aggregation: both branches, 16-deep unrolled fp8 gather
  dim3 agrid(N_NODES / 4, 2);
  k_agg<<<agrid, 256, 0, stream>>>(h, dinv_l, dinv_g, row_l, row_g, er_l, er_g, bl1, bg1, xl);

  // pool2 (PCH=256 -> 196 chunks x 2; Spart aliased over dead part[])
  dim3 pgrid(NCHUNK, 2);
  k_pool2<<<pgrid, 256, 0, stream>>>(xl, c_l, c_g, Spart);
  k_pool_reduce<<<(2 * 16384 + 255) / 256, 256, 0, stream>>>(Spart, S);

  k_final<<<N_GRAPHS, OUT_DIM, 0, stream>>>(S, Wl2, bl2, Wg2, bg2, Wf, bf, start, out);
}